// Round 1
// baseline (1422.062 us; speedup 1.0000x reference)
//
#include <hip/hip_runtime.h>

#define NU0 20000
#define NI0 15000
#define NN0 35000
#define NU1 4000
#define NI1 3000
#define NN1 7000
#define EE0 1000000
#define EE1 200000
#define KP_I 3008   // 3000 padded to mult of 32

typedef _Float16 f16;
typedef _Float16 f16x4 __attribute__((ext_vector_type(4)));
typedef _Float16 f16x8 __attribute__((ext_vector_type(8)));
typedef float f32x4 __attribute__((ext_vector_type(4)));

// ---------------------------------------------------------------- init: ego = [ue;ie], also all_e[:,0:64]
__global__ void k_init_ego(const float* __restrict__ ue, const float* __restrict__ ie,
                           int nu, int n, float* __restrict__ ego, float* __restrict__ alle) {
    int tid = blockIdx.x * blockDim.x + threadIdx.x;
    if (tid >= n * 64) return;
    int row = tid >> 6, c = tid & 63;
    float v = (row < nu) ? ue[tid] : ie[tid - nu * 64];
    ego[tid] = v;
    alle[(size_t)row * 256 + c] = v;
}

// ---------------------------------------------------------------- CSR build
__global__ void k_hist(const int* __restrict__ rows, int e, int* __restrict__ cnt) {
    int tid = blockIdx.x * blockDim.x + threadIdx.x;
    if (tid < e) atomicAdd(&cnt[rows[tid]], 1);
}

__global__ __launch_bounds__(1024) void k_scan(const int* __restrict__ cnt, int n,
                                               int* __restrict__ rowptr, int* __restrict__ fill) {
    __shared__ int sm[1024];
    __shared__ int carry;
    int tid = threadIdx.x;
    if (tid == 0) { carry = 0; rowptr[0] = 0; }
    __syncthreads();
    for (int base = 0; base < n; base += 1024) {
        int i = base + tid;
        int v = (i < n) ? cnt[i] : 0;
        sm[tid] = v;
        __syncthreads();
        for (int off = 1; off < 1024; off <<= 1) {
            int t = (tid >= off) ? sm[tid - off] : 0;
            __syncthreads();
            sm[tid] += t;
            __syncthreads();
        }
        int incl = sm[tid];
        int total = sm[1023];
        int c = carry;
        if (i < n) { rowptr[i + 1] = c + incl; fill[i] = c + incl - v; }
        __syncthreads();
        if (tid == 0) carry += total;
        __syncthreads();
    }
}

__global__ void k_scatter(const int* __restrict__ rows, const int* __restrict__ cols,
                          const float* __restrict__ vals, int e, int* __restrict__ fill,
                          int* __restrict__ colss, float* __restrict__ valss) {
    int tid = blockIdx.x * blockDim.x + threadIdx.x;
    if (tid < e) {
        int r = rows[tid];
        int pos = atomicAdd(&fill[r], 1);
        colss[pos] = cols[tid];
        valss[pos] = vals[tid];
    }
}

// ---------------------------------------------------------------- SpMM: one wave per row, lane = dim
__global__ void k_spmm(const int* __restrict__ rowptr, const int* __restrict__ colss,
                       const float* __restrict__ valss, const float* __restrict__ ego,
                       float* __restrict__ side, int nrows) {
    int gw = (blockIdx.x * blockDim.x + threadIdx.x) >> 6;
    int lane = threadIdx.x & 63;
    if (gw >= nrows) return;
    int s = rowptr[gw];
    int e = rowptr[gw + 1];
    s = __builtin_amdgcn_readfirstlane(s);
    e = __builtin_amdgcn_readfirstlane(e);
    float acc = 0.f;
    for (int i = s; i < e; ++i) {
        int c = colss[i];
        float v = valss[i];
        acc += v * ego[(size_t)c * 64 + lane];
    }
    side[(size_t)gw * 64 + lane] = acc;
}

// ---------------------------------------------------------------- dense layer: MFMA f16, fused leaky+bi+norm
#define DPAD 72
__global__ __launch_bounds__(256) void k_dense(
    const float* __restrict__ side, float* __restrict__ ego,
    const float* __restrict__ Wg, const float* __restrict__ bg,
    const float* __restrict__ Wb, const float* __restrict__ bb,
    float* __restrict__ alle, int col_off, int nrows) {
    __shared__ f16 sS[64 * DPAD];
    __shared__ f16 sM[64 * DPAD];
    __shared__ f16 sWg[64 * DPAD];  // transposed [n][k]
    __shared__ f16 sWb[64 * DPAD];
    int tid = threadIdx.x;
    int m0 = blockIdx.x * 64;
#pragma unroll
    for (int j = 0; j < 16; j++) {
        int idx = j * 256 + tid;
        int k = idx >> 6, nn = idx & 63;
        sWg[nn * DPAD + k] = (f16)Wg[idx];
        sWb[nn * DPAD + k] = (f16)Wb[idx];
    }
    {
        int row = tid >> 2;
        int seg = (tid & 3) * 16;
        bool rok = (m0 + row) < nrows;
        const float4* sp = (const float4*)(side + (size_t)(m0 + row) * 64 + seg);
        const float4* ep = (const float4*)(ego + (size_t)(m0 + row) * 64 + seg);
#pragma unroll
        for (int j = 0; j < 4; j++) {
            float4 sv = rok ? sp[j] : make_float4(0.f, 0.f, 0.f, 0.f);
            float4 ev = rok ? ep[j] : make_float4(0.f, 0.f, 0.f, 0.f);
            f16x4 a, m;
            a[0] = (f16)sv.x; a[1] = (f16)sv.y; a[2] = (f16)sv.z; a[3] = (f16)sv.w;
            m[0] = (f16)(sv.x * ev.x); m[1] = (f16)(sv.y * ev.y);
            m[2] = (f16)(sv.z * ev.z); m[3] = (f16)(sv.w * ev.w);
            int kk = seg + j * 4;
            *(f16x4*)&sS[row * DPAD + kk] = a;
            *(f16x4*)&sM[row * DPAD + kk] = m;
        }
    }
    __syncthreads();
    int lane = tid & 63, wv = tid >> 6;
    int lr = lane & 15, quad = lane >> 4;
    int wm = wv * 16;
    f32x4 zero = {0.f, 0.f, 0.f, 0.f};
    f32x4 accA[4], accB[4];
#pragma unroll
    for (int j = 0; j < 4; j++) { accA[j] = zero; accB[j] = zero; }
#pragma unroll
    for (int k0 = 0; k0 < 64; k0 += 32) {
        f16x8 af = *(f16x8*)&sS[(wm + lr) * DPAD + k0 + quad * 8];
        f16x8 mf = *(f16x8*)&sM[(wm + lr) * DPAD + k0 + quad * 8];
#pragma unroll
        for (int j = 0; j < 4; j++) {
            f16x8 bgf = *(f16x8*)&sWg[(j * 16 + lr) * DPAD + k0 + quad * 8];
            f16x8 bbf = *(f16x8*)&sWb[(j * 16 + lr) * DPAD + k0 + quad * 8];
            accA[j] = __builtin_amdgcn_mfma_f32_16x16x32_f16(af, bgf, accA[j], 0, 0, 0);
            accB[j] = __builtin_amdgcn_mfma_f32_16x16x32_f16(mf, bbf, accB[j], 0, 0, 0);
        }
    }
    float e[4][4];
    float sq[4] = {0.f, 0.f, 0.f, 0.f};
#pragma unroll
    for (int j = 0; j < 4; j++) {
        int col = j * 16 + lr;
        float bgv = bg[col], bbv = bb[col];
#pragma unroll
        for (int r = 0; r < 4; r++) {
            float a = accA[j][r] + bgv; a = (a > 0.f) ? a : 0.01f * a;
            float b = accB[j][r] + bbv; b = (b > 0.f) ? b : 0.01f * b;
            float ev = a + b;
            e[j][r] = ev;
            sq[r] += ev * ev;
        }
    }
#pragma unroll
    for (int msk = 1; msk < 16; msk <<= 1) {
#pragma unroll
        for (int r = 0; r < 4; r++) sq[r] += __shfl_xor(sq[r], msk, 64);
    }
#pragma unroll
    for (int r = 0; r < 4; r++) {
        int gr = m0 + wm + quad * 4 + r;
        if (gr < nrows) {
            float inv = 1.0f / fmaxf(sqrtf(sq[r]), 1e-12f);
#pragma unroll
            for (int j = 0; j < 4; j++) {
                int col = j * 16 + lr;
                ego[(size_t)gr * 64 + col] = e[j][r];
                alle[(size_t)gr * 256 + col_off + col] = e[j][r] * inv;
            }
        }
    }
}

// ---------------------------------------------------------------- transpose all_e1 block -> Bt [256][Kp] f16
__global__ void k_transpose(const float* __restrict__ src, f16* __restrict__ dst, int K, int Kp) {
    int k = blockIdx.x * blockDim.x + threadIdx.x;
    int nIdx = blockIdx.y;
    if (k < Kp)
        dst[(size_t)nIdx * Kp + k] = (k < K) ? (f16)src[(size_t)k * 256 + nIdx] : (f16)0.f;
}

// ---------------------------------------------------------------- big GEMM: out = A@B^T-of-Bt + C0
#define GPAD 40
__global__ __launch_bounds__(256) void k_gemm(
    const float* __restrict__ A, const f16* __restrict__ Bt,
    const float* __restrict__ C0, float* __restrict__ outp,
    int M, int K, int Kp) {
    __shared__ f16 sA[128 * GPAD];
    __shared__ f16 sB[128 * GPAD];
    int tid = threadIdx.x;
    int bm = blockIdx.x >> 1, bn = blockIdx.x & 1;
    int m0 = bm * 128, n0 = bn * 128;
    int lane = tid & 63, wv = tid >> 6;
    int lr = lane & 15, quad = lane >> 4;
    int wm = (wv >> 1) * 64, wn = (wv & 1) * 64;
    int srow = tid >> 1;
    int skh = (tid & 1) * 16;
    bool arow_ok = (m0 + srow) < M;
    const float* aptr = A + (size_t)(m0 + srow) * K + skh;
    const f16* bptr = Bt + (size_t)(n0 + srow) * Kp + skh;
    f32x4 zero = {0.f, 0.f, 0.f, 0.f};
    f32x4 acc[4][4];
#pragma unroll
    for (int i = 0; i < 4; i++)
#pragma unroll
        for (int j = 0; j < 4; j++) acc[i][j] = zero;
    for (int k0 = 0; k0 < Kp; k0 += 32) {
#pragma unroll
        for (int j = 0; j < 4; j++) {
            int kk = k0 + skh + j * 4;
            float4 v = make_float4(0.f, 0.f, 0.f, 0.f);
            if (arow_ok && kk < K) v = *(const float4*)(aptr + k0 + j * 4);
            f16x4 h;
            h[0] = (f16)v.x; h[1] = (f16)v.y; h[2] = (f16)v.z; h[3] = (f16)v.w;
            *(f16x4*)&sA[srow * GPAD + skh + j * 4] = h;
        }
        *(f16x8*)&sB[srow * GPAD + skh] = *(const f16x8*)(bptr + k0);
        *(f16x8*)&sB[srow * GPAD + skh + 8] = *(const f16x8*)(bptr + k0 + 8);
        __syncthreads();
        f16x8 af[4], bf[4];
#pragma unroll
        for (int i = 0; i < 4; i++) af[i] = *(f16x8*)&sA[(wm + i * 16 + lr) * GPAD + quad * 8];
#pragma unroll
        for (int j = 0; j < 4; j++) bf[j] = *(f16x8*)&sB[(wn + j * 16 + lr) * GPAD + quad * 8];
#pragma unroll
        for (int i = 0; i < 4; i++)
#pragma unroll
            for (int j = 0; j < 4; j++)
                acc[i][j] = __builtin_amdgcn_mfma_f32_16x16x32_f16(af[i], bf[j], acc[i][j], 0, 0, 0);
        __syncthreads();
    }
#pragma unroll
    for (int i = 0; i < 4; i++) {
#pragma unroll
        for (int r = 0; r < 4; r++) {
            int gr = m0 + wm + i * 16 + quad * 4 + r;
            if (gr < M) {
#pragma unroll
                for (int j = 0; j < 4; j++) {
                    int gc = n0 + wn + j * 16 + lr;
                    size_t off = (size_t)gr * 256 + gc;
                    outp[off] = acc[i][j][r] + C0[off];
                }
            }
        }
    }
}

// ---------------------------------------------------------------- host
extern "C" void kernel_launch(void* const* d_in, const int* in_sizes, int n_in,
                              void* d_out, int out_size, void* d_ws, size_t ws_size,
                              hipStream_t stream) {
    (void)in_sizes; (void)n_in; (void)out_size; (void)ws_size;
    const float* ue0  = (const float*)d_in[0];
    const float* ie0  = (const float*)d_in[1];
    const float* gcW0 = (const float*)d_in[2];
    const float* gcb0 = (const float*)d_in[3];
    const float* biW0 = (const float*)d_in[4];
    const float* bib0 = (const float*)d_in[5];
    const float* ue1  = (const float*)d_in[6];
    const float* ie1  = (const float*)d_in[7];
    const float* gcW1 = (const float*)d_in[8];
    const float* gcb1 = (const float*)d_in[9];
    const float* biW1 = (const float*)d_in[10];
    const float* bib1 = (const float*)d_in[11];
    const float* mapu = (const float*)d_in[12];
    const float* mapi = (const float*)d_in[13];
    const float* vals0 = (const float*)d_in[14];
    const float* vals1 = (const float*)d_in[15];
    const int* rows0 = (const int*)d_in[16];
    const int* cols0 = (const int*)d_in[17];
    const int* rows1 = (const int*)d_in[18];
    const int* cols1 = (const int*)d_in[19];
    float* out = (float*)d_out;

    char* p = (char*)d_ws;
    auto alloc = [&](size_t b) { char* r = p; p += (b + 255) & ~(size_t)255; return r; };
    float* ego0  = (float*)alloc((size_t)NN0 * 64 * 4);
    float* side0 = (float*)alloc((size_t)NN0 * 64 * 4);
    float* alle0 = (float*)alloc((size_t)NN0 * 256 * 4);
    float* ego1  = (float*)alloc((size_t)NN1 * 64 * 4);
    float* side1 = (float*)alloc((size_t)NN1 * 64 * 4);
    float* alle1 = (float*)alloc((size_t)NN1 * 256 * 4);
    int* cnt0    = (int*)alloc((size_t)NN0 * 4);
    int* ptr0    = (int*)alloc((size_t)(NN0 + 1) * 4);
    int* fill0   = (int*)alloc((size_t)NN0 * 4);
    int* colss0  = (int*)alloc((size_t)EE0 * 4);
    float* valss0 = (float*)alloc((size_t)EE0 * 4);
    int* cnt1    = (int*)alloc((size_t)NN1 * 4);
    int* ptr1    = (int*)alloc((size_t)(NN1 + 1) * 4);
    int* fill1   = (int*)alloc((size_t)NN1 * 4);
    int* colss1  = (int*)alloc((size_t)EE1 * 4);
    float* valss1 = (float*)alloc((size_t)EE1 * 4);
    f16* btu = (f16*)alloc((size_t)256 * 4000 * 2);
    f16* bti = (f16*)alloc((size_t)256 * KP_I * 2);

    hipMemsetAsync(cnt0, 0, (size_t)NN0 * 4, stream);
    hipMemsetAsync(cnt1, 0, (size_t)NN1 * 4, stream);

    k_init_ego<<<(NN0 * 64 + 255) / 256, 256, 0, stream>>>(ue0, ie0, NU0, NN0, ego0, alle0);
    k_init_ego<<<(NN1 * 64 + 255) / 256, 256, 0, stream>>>(ue1, ie1, NU1, NN1, ego1, alle1);

    k_hist<<<(EE0 + 255) / 256, 256, 0, stream>>>(rows0, EE0, cnt0);
    k_hist<<<(EE1 + 255) / 256, 256, 0, stream>>>(rows1, EE1, cnt1);
    k_scan<<<1, 1024, 0, stream>>>(cnt0, NN0, ptr0, fill0);
    k_scan<<<1, 1024, 0, stream>>>(cnt1, NN1, ptr1, fill1);
    k_scatter<<<(EE0 + 255) / 256, 256, 0, stream>>>(rows0, cols0, vals0, EE0, fill0, colss0, valss0);
    k_scatter<<<(EE1 + 255) / 256, 256, 0, stream>>>(rows1, cols1, vals1, EE1, fill1, colss1, valss1);

    for (int l = 0; l < 3; l++) {
        k_spmm<<<(NN0 * 64 + 255) / 256, 256, 0, stream>>>(ptr0, colss0, valss0, ego0, side0, NN0);
        k_dense<<<(NN0 + 63) / 64, 256, 0, stream>>>(side0, ego0, gcW0 + l * 4096, gcb0 + l * 64,
                                                     biW0 + l * 4096, bib0 + l * 64, alle0, (l + 1) * 64, NN0);
        k_spmm<<<(NN1 * 64 + 255) / 256, 256, 0, stream>>>(ptr1, colss1, valss1, ego1, side1, NN1);
        k_dense<<<(NN1 + 63) / 64, 256, 0, stream>>>(side1, ego1, gcW1 + l * 4096, gcb1 + l * 64,
                                                     biW1 + l * 4096, bib1 + l * 64, alle1, (l + 1) * 64, NN1);
    }

    dim3 tgu((4000 + 255) / 256, 256);
    k_transpose<<<tgu, 256, 0, stream>>>(alle1, btu, 4000, 4000);
    dim3 tgi((KP_I + 255) / 256, 256);
    k_transpose<<<tgi, 256, 0, stream>>>(alle1 + (size_t)4000 * 256, bti, 3000, KP_I);

    k_gemm<<<((NU0 + 127) / 128) * 2, 256, 0, stream>>>(mapu, btu, alle0, out, NU0, 4000, 4000);
    k_gemm<<<((NI0 + 127) / 128) * 2, 256, 0, stream>>>(mapi, bti, alle0 + (size_t)NU0 * 256,
                                                        out + (size_t)NU0 * 256, NI0, 3000, KP_I);
}

// Round 2
// 1203.812 us; speedup vs baseline: 1.1813x; 1.1813x over previous
//
#include <hip/hip_runtime.h>

#define NU0 20000
#define NI0 15000
#define NN0 35000
#define NU1 4000
#define NI1 3000
#define NN1 7000
#define EE0 1000000
#define EE1 200000
#define KP_I 3008   // 3000 padded to mult of 32
#define NSPLIT 4

typedef _Float16 f16;
typedef _Float16 f16x4 __attribute__((ext_vector_type(4)));
typedef _Float16 f16x8 __attribute__((ext_vector_type(8)));
typedef float f32x4 __attribute__((ext_vector_type(4)));

// ---------------------------------------------------------------- init: ego = [ue;ie], also all_e[:,0:64]
__global__ void k_init_ego(const float* __restrict__ ue, const float* __restrict__ ie,
                           int nu, int n, float* __restrict__ ego, float* __restrict__ alle) {
    int tid = blockIdx.x * blockDim.x + threadIdx.x;
    if (tid >= n * 64) return;
    int row = tid >> 6, c = tid & 63;
    float v = (row < nu) ? ue[tid] : ie[tid - nu * 64];
    ego[tid] = v;
    alle[(size_t)row * 256 + c] = v;
}

// ---------------------------------------------------------------- CSR build
__global__ void k_hist(const int* __restrict__ rows, int e, int* __restrict__ cnt) {
    int tid = blockIdx.x * blockDim.x + threadIdx.x;
    if (tid < e) atomicAdd(&cnt[rows[tid]], 1);
}

// shuffle-based scan: 2 barriers per 1024-tile instead of 20
__global__ __launch_bounds__(1024) void k_scan(const int* __restrict__ cnt, int n,
                                               int* __restrict__ rowptr, int* __restrict__ fill) {
    __shared__ int wsum[16];
    __shared__ int carry_s;
    int tid = threadIdx.x;
    int lane = tid & 63, wv = tid >> 6;
    if (tid == 0) { carry_s = 0; rowptr[0] = 0; }
    __syncthreads();
    for (int base = 0; base < n; base += 1024) {
        int i = base + tid;
        int v = (i < n) ? cnt[i] : 0;
        int x = v;
#pragma unroll
        for (int off = 1; off < 64; off <<= 1) {
            int t = __shfl_up(x, off, 64);
            if (lane >= off) x += t;
        }
        if (lane == 63) wsum[wv] = x;
        __syncthreads();
        if (wv == 0 && lane < 16) {
            int y = wsum[lane];
#pragma unroll
            for (int off = 1; off < 16; off <<= 1) {
                int t = __shfl_up(y, off, 16);
                if (lane >= off) y += t;
            }
            wsum[lane] = y;
        }
        __syncthreads();
        int blocksum = wsum[15];
        int incl = x + (wv ? wsum[wv - 1] : 0);
        int c = carry_s;
        if (i < n) { rowptr[i + 1] = c + incl; fill[i] = c + incl - v; }
        __syncthreads();
        if (tid == 0) carry_s += blocksum;
        __syncthreads();
    }
}

__global__ void k_scatter(const int* __restrict__ rows, const int* __restrict__ cols,
                          const float* __restrict__ vals, int e, int* __restrict__ fill,
                          int* __restrict__ colss, float* __restrict__ valss) {
    int tid = blockIdx.x * blockDim.x + threadIdx.x;
    if (tid < e) {
        int r = rows[tid];
        int pos = atomicAdd(&fill[r], 1);
        colss[pos] = cols[tid];
        valss[pos] = vals[tid];
    }
}

// ---------------------------------------------------------------- SpMM: one wave per row, lane = dim
// 4-wide unroll: 4 independent gathers in flight per iteration
__global__ void k_spmm(const int* __restrict__ rowptr, const int* __restrict__ colss,
                       const float* __restrict__ valss, const float* __restrict__ ego,
                       float* __restrict__ side, int nrows) {
    int gw = (blockIdx.x * blockDim.x + threadIdx.x) >> 6;
    int lane = threadIdx.x & 63;
    if (gw >= nrows) return;
    int s = rowptr[gw];
    int e = rowptr[gw + 1];
    s = __builtin_amdgcn_readfirstlane(s);
    e = __builtin_amdgcn_readfirstlane(e);
    float acc = 0.f;
    int i = s;
    for (; i + 3 < e; i += 4) {
        int c0 = colss[i], c1 = colss[i + 1], c2 = colss[i + 2], c3 = colss[i + 3];
        float v0 = valss[i], v1 = valss[i + 1], v2 = valss[i + 2], v3 = valss[i + 3];
        float g0 = ego[(size_t)c0 * 64 + lane];
        float g1 = ego[(size_t)c1 * 64 + lane];
        float g2 = ego[(size_t)c2 * 64 + lane];
        float g3 = ego[(size_t)c3 * 64 + lane];
        acc += v0 * g0 + v1 * g1 + v2 * g2 + v3 * g3;
    }
    for (; i < e; ++i) {
        acc += valss[i] * ego[(size_t)colss[i] * 64 + lane];
    }
    side[(size_t)gw * 64 + lane] = acc;
}

// ---------------------------------------------------------------- dense layer: MFMA f16, fused leaky+bi+norm
#define DPAD 72
__global__ __launch_bounds__(256) void k_dense(
    const float* __restrict__ side, float* __restrict__ ego,
    const float* __restrict__ Wg, const float* __restrict__ bg,
    const float* __restrict__ Wb, const float* __restrict__ bb,
    float* __restrict__ alle, int col_off, int nrows) {
    __shared__ f16 sS[64 * DPAD];
    __shared__ f16 sM[64 * DPAD];
    __shared__ f16 sWg[64 * DPAD];  // transposed [n][k]
    __shared__ f16 sWb[64 * DPAD];
    int tid = threadIdx.x;
    int m0 = blockIdx.x * 64;
#pragma unroll
    for (int j = 0; j < 16; j++) {
        int idx = j * 256 + tid;
        int k = idx >> 6, nn = idx & 63;
        sWg[nn * DPAD + k] = (f16)Wg[idx];
        sWb[nn * DPAD + k] = (f16)Wb[idx];
    }
    {
        int row = tid >> 2;
        int seg = (tid & 3) * 16;
        bool rok = (m0 + row) < nrows;
        const float4* sp = (const float4*)(side + (size_t)(m0 + row) * 64 + seg);
        const float4* ep = (const float4*)(ego + (size_t)(m0 + row) * 64 + seg);
#pragma unroll
        for (int j = 0; j < 4; j++) {
            float4 sv = rok ? sp[j] : make_float4(0.f, 0.f, 0.f, 0.f);
            float4 ev = rok ? ep[j] : make_float4(0.f, 0.f, 0.f, 0.f);
            f16x4 a, m;
            a[0] = (f16)sv.x; a[1] = (f16)sv.y; a[2] = (f16)sv.z; a[3] = (f16)sv.w;
            m[0] = (f16)(sv.x * ev.x); m[1] = (f16)(sv.y * ev.y);
            m[2] = (f16)(sv.z * ev.z); m[3] = (f16)(sv.w * ev.w);
            int kk = seg + j * 4;
            *(f16x4*)&sS[row * DPAD + kk] = a;
            *(f16x4*)&sM[row * DPAD + kk] = m;
        }
    }
    __syncthreads();
    int lane = tid & 63, wv = tid >> 6;
    int lr = lane & 15, quad = lane >> 4;
    int wm = wv * 16;
    f32x4 zero = {0.f, 0.f, 0.f, 0.f};
    f32x4 accA[4], accB[4];
#pragma unroll
    for (int j = 0; j < 4; j++) { accA[j] = zero; accB[j] = zero; }
#pragma unroll
    for (int k0 = 0; k0 < 64; k0 += 32) {
        f16x8 af = *(f16x8*)&sS[(wm + lr) * DPAD + k0 + quad * 8];
        f16x8 mf = *(f16x8*)&sM[(wm + lr) * DPAD + k0 + quad * 8];
#pragma unroll
        for (int j = 0; j < 4; j++) {
            f16x8 bgf = *(f16x8*)&sWg[(j * 16 + lr) * DPAD + k0 + quad * 8];
            f16x8 bbf = *(f16x8*)&sWb[(j * 16 + lr) * DPAD + k0 + quad * 8];
            accA[j] = __builtin_amdgcn_mfma_f32_16x16x32_f16(af, bgf, accA[j], 0, 0, 0);
            accB[j] = __builtin_amdgcn_mfma_f32_16x16x32_f16(mf, bbf, accB[j], 0, 0, 0);
        }
    }
    float e[4][4];
    float sq[4] = {0.f, 0.f, 0.f, 0.f};
#pragma unroll
    for (int j = 0; j < 4; j++) {
        int col = j * 16 + lr;
        float bgv = bg[col], bbv = bb[col];
#pragma unroll
        for (int r = 0; r < 4; r++) {
            float a = accA[j][r] + bgv; a = (a > 0.f) ? a : 0.01f * a;
            float b = accB[j][r] + bbv; b = (b > 0.f) ? b : 0.01f * b;
            float ev = a + b;
            e[j][r] = ev;
            sq[r] += ev * ev;
        }
    }
#pragma unroll
    for (int msk = 1; msk < 16; msk <<= 1) {
#pragma unroll
        for (int r = 0; r < 4; r++) sq[r] += __shfl_xor(sq[r], msk, 64);
    }
#pragma unroll
    for (int r = 0; r < 4; r++) {
        int gr = m0 + wm + quad * 4 + r;
        if (gr < nrows) {
            float inv = 1.0f / fmaxf(sqrtf(sq[r]), 1e-12f);
#pragma unroll
            for (int j = 0; j < 4; j++) {
                int col = j * 16 + lr;
                ego[(size_t)gr * 64 + col] = e[j][r];
                alle[(size_t)gr * 256 + col_off + col] = e[j][r] * inv;
            }
        }
    }
}

// ---------------------------------------------------------------- transpose all_e1 block -> Bt [256][Kp] f16
__global__ void k_transpose(const float* __restrict__ src, f16* __restrict__ dst, int K, int Kp) {
    int k = blockIdx.x * blockDim.x + threadIdx.x;
    int nIdx = blockIdx.y;
    if (k < Kp)
        dst[(size_t)nIdx * Kp + k] = (k < K) ? (f16)src[(size_t)k * 256 + nIdx] : (f16)0.f;
}

// ---------------------------------------------------------------- big GEMM (split-K): out += A@Bt^T via atomicAdd
// out must already contain the C0 term (alle0 is aliased onto d_out).
#define GPAD 40
__global__ __launch_bounds__(256) void k_gemm(
    const float* __restrict__ A, const f16* __restrict__ Bt,
    float* __restrict__ outp, int M, int K, int Kp) {
    __shared__ f16 sA[128 * GPAD];
    __shared__ f16 sB[128 * GPAD];
    int tid = threadIdx.x;
    int split = blockIdx.x % NSPLIT;
    int t = blockIdx.x / NSPLIT;
    int bm = t >> 1, bn = t & 1;
    int m0 = bm * 128, n0 = bn * 128;
    int chunk = ((Kp / 32 + NSPLIT - 1) / NSPLIT) * 32;
    int kbeg = split * chunk;
    int kend = min(Kp, kbeg + chunk);
    int lane = tid & 63, wv = tid >> 6;
    int lr = lane & 15, quad = lane >> 4;
    int wm = (wv >> 1) * 64, wn = (wv & 1) * 64;
    int srow = tid >> 1;
    int skh = (tid & 1) * 16;
    bool arow_ok = (m0 + srow) < M;
    const float* aptr = A + (size_t)(m0 + srow) * K + skh;
    const f16* bptr = Bt + (size_t)(n0 + srow) * Kp + skh;
    f32x4 zero = {0.f, 0.f, 0.f, 0.f};
    f32x4 acc[4][4];
#pragma unroll
    for (int i = 0; i < 4; i++)
#pragma unroll
        for (int j = 0; j < 4; j++) acc[i][j] = zero;
    for (int k0 = kbeg; k0 < kend; k0 += 32) {
#pragma unroll
        for (int j = 0; j < 4; j++) {
            int kk = k0 + skh + j * 4;
            float4 v = make_float4(0.f, 0.f, 0.f, 0.f);
            if (arow_ok && kk < K) v = *(const float4*)(aptr + k0 + j * 4);
            f16x4 h;
            h[0] = (f16)v.x; h[1] = (f16)v.y; h[2] = (f16)v.z; h[3] = (f16)v.w;
            *(f16x4*)&sA[srow * GPAD + skh + j * 4] = h;
        }
        *(f16x8*)&sB[srow * GPAD + skh] = *(const f16x8*)(bptr + k0);
        *(f16x8*)&sB[srow * GPAD + skh + 8] = *(const f16x8*)(bptr + k0 + 8);
        __syncthreads();
        f16x8 af[4], bf[4];
#pragma unroll
        for (int i = 0; i < 4; i++) af[i] = *(f16x8*)&sA[(wm + i * 16 + lr) * GPAD + quad * 8];
#pragma unroll
        for (int j = 0; j < 4; j++) bf[j] = *(f16x8*)&sB[(wn + j * 16 + lr) * GPAD + quad * 8];
#pragma unroll
        for (int i = 0; i < 4; i++)
#pragma unroll
            for (int j = 0; j < 4; j++)
                acc[i][j] = __builtin_amdgcn_mfma_f32_16x16x32_f16(af[i], bf[j], acc[i][j], 0, 0, 0);
        __syncthreads();
    }
#pragma unroll
    for (int i = 0; i < 4; i++) {
#pragma unroll
        for (int r = 0; r < 4; r++) {
            int gr = m0 + wm + i * 16 + quad * 4 + r;
            if (gr < M) {
#pragma unroll
                for (int j = 0; j < 4; j++) {
                    int gc = n0 + wn + j * 16 + lr;
                    size_t off = (size_t)gr * 256 + gc;
                    atomicAdd(&outp[off], acc[i][j][r]);
                }
            }
        }
    }
}

// ---------------------------------------------------------------- host
extern "C" void kernel_launch(void* const* d_in, const int* in_sizes, int n_in,
                              void* d_out, int out_size, void* d_ws, size_t ws_size,
                              hipStream_t stream) {
    (void)in_sizes; (void)n_in; (void)out_size; (void)ws_size;
    const float* ue0  = (const float*)d_in[0];
    const float* ie0  = (const float*)d_in[1];
    const float* gcW0 = (const float*)d_in[2];
    const float* gcb0 = (const float*)d_in[3];
    const float* biW0 = (const float*)d_in[4];
    const float* bib0 = (const float*)d_in[5];
    const float* ue1  = (const float*)d_in[6];
    const float* ie1  = (const float*)d_in[7];
    const float* gcW1 = (const float*)d_in[8];
    const float* gcb1 = (const float*)d_in[9];
    const float* biW1 = (const float*)d_in[10];
    const float* bib1 = (const float*)d_in[11];
    const float* mapu = (const float*)d_in[12];
    const float* mapi = (const float*)d_in[13];
    const float* vals0 = (const float*)d_in[14];
    const float* vals1 = (const float*)d_in[15];
    const int* rows0 = (const int*)d_in[16];
    const int* cols0 = (const int*)d_in[17];
    const int* rows1 = (const int*)d_in[18];
    const int* cols1 = (const int*)d_in[19];
    float* out = (float*)d_out;

    char* p = (char*)d_ws;
    auto alloc = [&](size_t b) { char* r = p; p += (b + 255) & ~(size_t)255; return r; };
    float* ego0  = (float*)alloc((size_t)NN0 * 64 * 4);
    float* side0 = (float*)alloc((size_t)NN0 * 64 * 4);
    float* alle0 = out;   // alias: all_e for graph0 accumulates directly into d_out
    float* ego1  = (float*)alloc((size_t)NN1 * 64 * 4);
    float* side1 = (float*)alloc((size_t)NN1 * 64 * 4);
    float* alle1 = (float*)alloc((size_t)NN1 * 256 * 4);
    int* cnt0    = (int*)alloc((size_t)NN0 * 4);
    int* ptr0    = (int*)alloc((size_t)(NN0 + 1) * 4);
    int* fill0   = (int*)alloc((size_t)NN0 * 4);
    int* colss0  = (int*)alloc((size_t)EE0 * 4);
    float* valss0 = (float*)alloc((size_t)EE0 * 4);
    int* cnt1    = (int*)alloc((size_t)NN1 * 4);
    int* ptr1    = (int*)alloc((size_t)(NN1 + 1) * 4);
    int* fill1   = (int*)alloc((size_t)NN1 * 4);
    int* colss1  = (int*)alloc((size_t)EE1 * 4);
    float* valss1 = (float*)alloc((size_t)EE1 * 4);
    f16* btu = (f16*)alloc((size_t)256 * 4000 * 2);
    f16* bti = (f16*)alloc((size_t)256 * KP_I * 2);

    hipMemsetAsync(cnt0, 0, (size_t)NN0 * 4, stream);
    hipMemsetAsync(cnt1, 0, (size_t)NN1 * 4, stream);

    k_init_ego<<<(NN0 * 64 + 255) / 256, 256, 0, stream>>>(ue0, ie0, NU0, NN0, ego0, alle0);
    k_init_ego<<<(NN1 * 64 + 255) / 256, 256, 0, stream>>>(ue1, ie1, NU1, NN1, ego1, alle1);

    k_hist<<<(EE0 + 255) / 256, 256, 0, stream>>>(rows0, EE0, cnt0);
    k_hist<<<(EE1 + 255) / 256, 256, 0, stream>>>(rows1, EE1, cnt1);
    k_scan<<<1, 1024, 0, stream>>>(cnt0, NN0, ptr0, fill0);
    k_scan<<<1, 1024, 0, stream>>>(cnt1, NN1, ptr1, fill1);
    k_scatter<<<(EE0 + 255) / 256, 256, 0, stream>>>(rows0, cols0, vals0, EE0, fill0, colss0, valss0);
    k_scatter<<<(EE1 + 255) / 256, 256, 0, stream>>>(rows1, cols1, vals1, EE1, fill1, colss1, valss1);

    for (int l = 0; l < 3; l++) {
        k_spmm<<<(NN0 * 64 + 255) / 256, 256, 0, stream>>>(ptr0, colss0, valss0, ego0, side0, NN0);
        k_dense<<<(NN0 + 63) / 64, 256, 0, stream>>>(side0, ego0, gcW0 + l * 4096, gcb0 + l * 64,
                                                     biW0 + l * 4096, bib0 + l * 64, alle0, (l + 1) * 64, NN0);
        k_spmm<<<(NN1 * 64 + 255) / 256, 256, 0, stream>>>(ptr1, colss1, valss1, ego1, side1, NN1);
        k_dense<<<(NN1 + 63) / 64, 256, 0, stream>>>(side1, ego1, gcW1 + l * 4096, gcb1 + l * 64,
                                                     biW1 + l * 4096, bib1 + l * 64, alle1, (l + 1) * 64, NN1);
    }

    dim3 tgu((4000 + 255) / 256, 256);
    k_transpose<<<tgu, 256, 0, stream>>>(alle1, btu, 4000, 4000);
    dim3 tgi((KP_I + 255) / 256, 256);
    k_transpose<<<tgi, 256, 0, stream>>>(alle1 + (size_t)4000 * 256, bti, 3000, KP_I);

    k_gemm<<<((NU0 + 127) / 128) * 2 * NSPLIT, 256, 0, stream>>>(mapu, btu, out, NU0, 4000, 4000);
    k_gemm<<<((NI0 + 127) / 128) * 2 * NSPLIT, 256, 0, stream>>>(mapi, bti,
                                                        out + (size_t)NU0 * 256, NI0, 3000, KP_I);
}